// Round 7
// baseline (647.835 us; speedup 1.0000x reference)
//
#include <hip/hip_runtime.h>

// EncoderDecoderLSTM on MI355X — R7: 16-wave gate-split pipeline (R5 shape)
// rebuilt to fit the 128-reg/wave budget for 4 waves/SIMD (R5 had ~190 live
// -> 62MB spill; R6 proved 2 waves/SIMD is stall-bound at ~48% idle).
// 1024 thr, BT=16, grid 256 (1 block/CU, 4 waves/SIMD).
// Waves 0-7: layer0 slot s; waves 8-15: layer1 slot s-1.
// Per wave: 2 gate-tiles. Register diet:
//  - L0: Whh0 hi+lo (mm3);  L1: Wih1 hi + Whh1 hi (mm2) — one overlay array Wx
//    serves as "Whh0-lo" (L0) / "Whh1-hi" (L1): weights = 32 regs both paths.
//  - stepB frags sequenced (h0 frags -> 8 MFMA -> reuse for h1 frags): peak 16.
//  - static parity (R6 unroll x2): no parity temps.
// Activation split by acc row via LDS float2 exchange (R5-verified), 2 barriers/slot.
// h planes keep f16 hi+lo; c-state fp32 in regs; native v_exp/v_rcp activations.

typedef _Float16 f16x8 __attribute__((ext_vector_type(8)));
typedef float    f32x4 __attribute__((ext_vector_type(4)));

static constexpr int T_ENC = 365;
static constexpr int HZ    = 7;
static constexpr int BT    = 16;   // batch rows per block
static constexpr int HPAD  = 72;   // padded f16 row stride (144 B)
static constexpr int EXP2  = 65;   // exch row stride in float2

#if __has_builtin(__builtin_amdgcn_exp2f)
__device__ __forceinline__ float fexp2(float x) { return __builtin_amdgcn_exp2f(x); }
#else
__device__ __forceinline__ float fexp2(float x) { return __exp2f(x); }
#endif
#if __has_builtin(__builtin_amdgcn_rcpf)
__device__ __forceinline__ float frcp(float x) { return __builtin_amdgcn_rcpf(x); }
#else
__device__ __forceinline__ float frcp(float x) { return 1.0f / x; }
#endif

__device__ __forceinline__ float sigf(float v) {
  return frcp(1.0f + fexp2(v * -1.442695040888963f));
}
__device__ __forceinline__ float tanh_fast(float v) {
  v = fminf(fmaxf(v, -30.0f), 30.0f);
  float t = fexp2(v * 2.885390081777927f);
  return (t - 1.0f) * frcp(t + 1.0f);
}

// acc += (Ahi+Alo) * W   (W single-plane)
__device__ __forceinline__ f32x4 mm2(f16x8 ahi, f16x8 alo, f16x8 w, f32x4 acc) {
  acc = __builtin_amdgcn_mfma_f32_16x16x32_f16(ahi, w, acc, 0, 0, 0);
  acc = __builtin_amdgcn_mfma_f32_16x16x32_f16(alo, w, acc, 0, 0, 0);
  return acc;
}
// acc += (Ahi+Alo)*(Whi+Wlo) dropping lo*lo
__device__ __forceinline__ f32x4 mm3(f16x8 ahi, f16x8 alo, f16x8 whi, f16x8 wlo, f32x4 acc) {
  acc = __builtin_amdgcn_mfma_f32_16x16x32_f16(ahi, whi, acc, 0, 0, 0);
  acc = __builtin_amdgcn_mfma_f32_16x16x32_f16(ahi, wlo, acc, 0, 0, 0);
  acc = __builtin_amdgcn_mfma_f32_16x16x32_f16(alo, whi, acc, 0, 0, 0);
  return acc;
}

__global__ __launch_bounds__(1024) __attribute__((amdgpu_waves_per_eu(4, 4)))
void lstm_fused(const float* __restrict__ x,
                const float* __restrict__ eWih0, const float* __restrict__ eWhh0,
                const float* __restrict__ eb0,
                const float* __restrict__ eWih1, const float* __restrict__ eWhh1,
                const float* __restrict__ eb1,
                const float* __restrict__ dWih0, const float* __restrict__ dWhh0,
                const float* __restrict__ db0,
                const float* __restrict__ dWih1, const float* __restrict__ dWhh1,
                const float* __restrict__ db1,
                const float* __restrict__ fcW, const float* __restrict__ fcb,
                float* __restrict__ out)
{
  __shared__ __align__(16) float    xs[T_ENC * BT];
  __shared__ __align__(16) _Float16 h0hi[2][BT * HPAD], h0lo[2][BT * HPAD];
  __shared__ __align__(16) _Float16 h1hi[2][BT * HPAD], h1lo[2][BT * HPAD];
  __shared__ __align__(16) float2   exch[2][16 * EXP2];
  __shared__ __align__(16) float    dins[BT];

  const int tid  = threadIdx.x;
  const int lane = tid & 63;
  const int wv   = tid >> 6;        // 0..15
  const int L    = wv >> 3;         // 0 = layer0 group, 1 = layer1 group
  const int w8   = wv & 7;
  const int wg   = w8 & 3;          // j-tile
  const int half = w8 >> 2;         // 0: gates i,f ; 1: gates g,o
  const int n    = lane & 15;
  const int q    = lane >> 4;
  const int b0g  = blockIdx.x * BT;
  const int wbase = wg * 16 + n;    // hidden column this lane publishes
  const int row0  = q * 4;          // lane's base acc (batch) row
  const int nH    = n * HPAD;

  for (int i = tid; i < T_ENC * BT; i += 1024) {
    int b = i / T_ENC;
    int t = i - b * T_ENC;
    xs[t * BT + b] = x[(b0g + b) * T_ENC + t];
  }
  for (int i = tid; i < 2 * BT * HPAD; i += 1024) {
    ((_Float16*)h0hi)[i] = (_Float16)0.f; ((_Float16*)h0lo)[i] = (_Float16)0.f;
    ((_Float16*)h1hi)[i] = (_Float16)0.f; ((_Float16*)h1lo)[i] = (_Float16)0.f;
  }
  if (tid < BT) dins[tid] = 0.f;

  // Weights: 2 gate-tiles per wave, gate rows r = ((half*2+ti)*4+wg)*16+n.
  //  L0: Whi = Whh0-hi, Wx = Whh0-lo (mm3) ; wih0v, biasv = b0
  //  L1: Whi = Wih1-hi, Wx = Whh1-hi (mm2) ; biasv = b1
  f16x8 Whi[2][2], Wx[2][2];
  float biasv[2], wih0v[2];

  auto splitrow = [&](const float* p, f16x8& hi, f16x8& lo) {
    #pragma unroll
    for (int j = 0; j < 8; ++j) {
      float v = p[j];
      _Float16 h = (_Float16)v;
      hi[j] = h; lo[j] = (_Float16)(v - (float)h);
    }
  };
  auto cvtrow = [&](const float* p, f16x8& hi) {
    #pragma unroll
    for (int j = 0; j < 8; ++j) hi[j] = (_Float16)p[j];
  };
  auto loadA = [&](const float* Wih0_, const float* Whh0_, const float* b0_) {
    #pragma unroll
    for (int ti = 0; ti < 2; ++ti) {
      const int r = ((half * 2 + ti) * 4 + wg) * 16 + n;
      biasv[ti] = b0_[r];
      wih0v[ti] = Wih0_[r];
      #pragma unroll
      for (int kc = 0; kc < 2; ++kc)
        splitrow(Whh0_ + r * 64 + kc * 32 + q * 8, Whi[ti][kc], Wx[ti][kc]);
    }
  };
  auto loadB = [&](const float* Wih1_, const float* Whh1_, const float* b1_) {
    #pragma unroll
    for (int ti = 0; ti < 2; ++ti) {
      const int r = ((half * 2 + ti) * 4 + wg) * 16 + n;
      biasv[ti] = b1_[r];
      #pragma unroll
      for (int kc = 0; kc < 2; ++kc) {
        cvtrow(Wih1_ + r * 64 + kc * 32 + q * 8, Whi[ti][kc]);
        cvtrow(Whh1_ + r * 64 + kc * 32 + q * 8, Wx[ti][kc]);
      }
    }
  };

  if (L == 0) loadA(eWih0, eWhh0, eb0);
  else        loadB(eWih1, eWhh1, eb1);

  float cs0 = 0.f, cs1 = 0.f;   // c for this lane's 2 owned rows

  // L0 gates: bias + x*wih0 + h0 @ Whh0 (hi+lo weights, mm3)
  auto stepA_mm = [&](const _Float16* Hh, const _Float16* Hl, f32x4 xv, f32x4* g2) {
    const _Float16* hp = Hh + nH;
    const _Float16* lp = Hl + nH;
    f16x8 ah0 = *(const f16x8*)(hp + q * 8);
    f16x8 ah1 = *(const f16x8*)(hp + 32 + q * 8);
    f16x8 al0 = *(const f16x8*)(lp + q * 8);
    f16x8 al1 = *(const f16x8*)(lp + 32 + q * 8);
    #pragma unroll
    for (int ti = 0; ti < 2; ++ti) {
      f32x4 a;
      #pragma unroll
      for (int r = 0; r < 4; ++r) a[r] = xv[r] * wih0v[ti] + biasv[ti];
      a = mm3(ah0, al0, Whi[ti][0], Wx[ti][0], a);
      a = mm3(ah1, al1, Whi[ti][1], Wx[ti][1], a);
      g2[ti] = a;
    }
  };
  // L1 gates: bias + h0 @ Wih1 + h1 @ Whh1 (hi-only weights, mm2).
  // Frags sequenced: h0 set -> 8 MFMAs -> same regs reused for h1 set.
  auto stepB_mm = [&](const _Float16* H0h, const _Float16* H0l,
                      const _Float16* H1h, const _Float16* H1l, f32x4* g2) {
    {
      const _Float16* hp = H0h + nH;
      const _Float16* lp = H0l + nH;
      f16x8 fh0 = *(const f16x8*)(hp + q * 8);
      f16x8 fh1 = *(const f16x8*)(hp + 32 + q * 8);
      f16x8 fl0 = *(const f16x8*)(lp + q * 8);
      f16x8 fl1 = *(const f16x8*)(lp + 32 + q * 8);
      #pragma unroll
      for (int ti = 0; ti < 2; ++ti) {
        f32x4 a;
        #pragma unroll
        for (int r = 0; r < 4; ++r) a[r] = biasv[ti];
        a = mm2(fh0, fl0, Whi[ti][0], a);
        a = mm2(fh1, fl1, Whi[ti][1], a);
        g2[ti] = a;
      }
    }
    {
      const _Float16* hp = H1h + nH;
      const _Float16* lp = H1l + nH;
      f16x8 fh0 = *(const f16x8*)(hp + q * 8);
      f16x8 fh1 = *(const f16x8*)(hp + 32 + q * 8);
      f16x8 fl0 = *(const f16x8*)(lp + q * 8);
      f16x8 fl1 = *(const f16x8*)(lp + 32 + q * 8);
      #pragma unroll
      for (int ti = 0; ti < 2; ++ti) {
        f32x4 a = g2[ti];
        a = mm2(fh0, fl0, Wx[ti][0], a);
        a = mm2(fh1, fl1, Wx[ti][1], a);
        g2[ti] = a;
      }
    }
  };

  // act phase 1: transcendentals on own 2 gates; ship the 2 rows partner owns
  auto act_pre = [&](const f32x4* g2, float* sv0, float* sv1) {
    if (half == 0) {   // own i,f ; ship rows row0+2, row0+3
      #pragma unroll
      for (int r = 0; r < 4; ++r) { sv0[r] = sigf(g2[0][r]); sv1[r] = sigf(g2[1][r]); }
      exch[L][(row0 + 2) * EXP2 + wbase] = make_float2(sv0[2], sv1[2]);
      exch[L][(row0 + 3) * EXP2 + wbase] = make_float2(sv0[3], sv1[3]);
    } else {           // own g,o ; ship rows row0+0, row0+1
      #pragma unroll
      for (int r = 0; r < 4; ++r) { sv0[r] = tanh_fast(g2[0][r]); sv1[r] = sigf(g2[1][r]); }
      exch[L][(row0 + 0) * EXP2 + wbase] = make_float2(sv0[0], sv1[0]);
      exch[L][(row0 + 1) * EXP2 + wbase] = make_float2(sv0[1], sv1[1]);
    }
  };
  // act phase 2 (post-barrier): c/h update for this wave's 2 rows + publish
  auto act_post = [&](const float* sv0, const float* sv1, _Float16* Oh, _Float16* Ol) {
    float si0, sf0, tg0, so0, si1, sf1, tg1, so1;
    int ra, rb;
    if (half == 0) {   // rows row0+0, row0+1 ; partner sent (tg, so)
      float2 e0 = exch[L][(row0 + 0) * EXP2 + wbase];
      float2 e1 = exch[L][(row0 + 1) * EXP2 + wbase];
      si0 = sv0[0]; sf0 = sv1[0]; tg0 = e0.x; so0 = e0.y;
      si1 = sv0[1]; sf1 = sv1[1]; tg1 = e1.x; so1 = e1.y;
      ra = row0; rb = row0 + 1;
    } else {           // rows row0+2, row0+3 ; partner sent (si, sf)
      float2 e0 = exch[L][(row0 + 2) * EXP2 + wbase];
      float2 e1 = exch[L][(row0 + 3) * EXP2 + wbase];
      si0 = e0.x; sf0 = e0.y; tg0 = sv0[2]; so0 = sv1[2];
      si1 = e1.x; sf1 = e1.y; tg1 = sv0[3]; so1 = sv1[3];
      ra = row0 + 2; rb = row0 + 3;
    }
    cs0 = sf0 * cs0 + si0 * tg0;
    float ha = so0 * tanh_fast(cs0);
    cs1 = sf1 * cs1 + si1 * tg1;
    float hb = so1 * tanh_fast(cs1);
    _Float16 pa = (_Float16)ha;
    Oh[ra * HPAD + wbase] = pa; Ol[ra * HPAD + wbase] = (_Float16)(ha - (float)pa);
    _Float16 pb = (_Float16)hb;
    Oh[rb * HPAD + wbase] = pb; Ol[rb * HPAD + wbase] = (_Float16)(hb - (float)pb);
  };

  __syncthreads();

  f32x4 g2[2];
  float sv0[4], sv1[4];

  // ---- prologue: slot 0 (even). L0: h0[1](zeros) -> h0[0]; L1 idle.
  if (L == 0) {
    f32x4 xv = *(const f32x4*)(xs + q * 4);
    stepA_mm(h0hi[1], h0lo[1], xv, g2);
    act_pre(g2, sv0, sv1);
  }
  __syncthreads();
  if (L == 0) act_post(sv0, sv1, h0hi[0], h0lo[0]);
  __syncthreads();

  // ---- main: slots 1..364 as 182 static-parity pairs; both groups active.
  for (int s = 1; s <= 363; s += 2) {
    // slot s (odd): L0 h0[0]->h0[1] ; L1 (t=s-1 even) h0[0],h1[1] -> h1[0]
    if (L == 0) {
      f32x4 xv = *(const f32x4*)(xs + s * BT + q * 4);
      stepA_mm(h0hi[0], h0lo[0], xv, g2);
    } else {
      stepB_mm(h0hi[0], h0lo[0], h1hi[1], h1lo[1], g2);
    }
    act_pre(g2, sv0, sv1);
    __syncthreads();
    if (L == 0) act_post(sv0, sv1, h0hi[1], h0lo[1]);
    else        act_post(sv0, sv1, h1hi[0], h1lo[0]);
    __syncthreads();
    // slot s+1 (even): L0 h0[1]->h0[0] ; L1 (t=s odd) h0[1],h1[0] -> h1[1]
    if (L == 0) {
      f32x4 xv = *(const f32x4*)(xs + (s + 1) * BT + q * 4);
      stepA_mm(h0hi[1], h0lo[1], xv, g2);
    } else {
      stepB_mm(h0hi[1], h0lo[1], h1hi[0], h1lo[0], g2);
    }
    act_pre(g2, sv0, sv1);
    __syncthreads();
    if (L == 0) act_post(sv0, sv1, h0hi[0], h0lo[0]);
    else        act_post(sv0, sv1, h1hi[1], h1lo[1]);
    __syncthreads();
  }

  // ---- epilogue: slot 365 (odd). L0 loads decoder weights; L1 (t=364 even):
  // h0[0], h1[1] -> h1[0].
  if (L == 0) {
    loadA(dWih0, dWhh0, db0);
  } else {
    stepB_mm(h0hi[0], h0lo[0], h1hi[1], h1lo[1], g2);
    act_pre(g2, sv0, sv1);
  }
  __syncthreads();
  if (L == 1) act_post(sv0, sv1, h1hi[0], h1lo[0]);
  __syncthreads();

  // ---- decoder ---- (latest h0(364), h1(364) in parity-0 buffers)
  if (L == 1) loadB(dWih1, dWhh1, db1);
  const float fcb0 = fcb[0];

  #pragma unroll 1
  for (int hz = 0; hz < HZ; ++hz) {
    const int p = hz & 1;
    if (L == 0) {
      f32x4 dv = *(const f32x4*)(dins + q * 4);
      stepA_mm(h0hi[p], h0lo[p], dv, g2);
      act_pre(g2, sv0, sv1);
    }
    __syncthreads();
    if (L == 0) act_post(sv0, sv1, h0hi[1 - p], h0lo[1 - p]);
    __syncthreads();
    if (L == 1) {
      stepB_mm(h0hi[1 - p], h0lo[1 - p], h1hi[p], h1lo[p], g2);
      act_pre(g2, sv0, sv1);
    }
    __syncthreads();
    if (L == 1) act_post(sv0, sv1, h1hi[1 - p], h1lo[1 - p]);
    __syncthreads();
    if (wv == 0) {
      const _Float16* Hh = h1hi[1 - p];
      const _Float16* Hl = h1lo[1 - p];
      f16x8 hh0 = *(const f16x8*)(Hh + nH + q * 16);
      f16x8 hh1 = *(const f16x8*)(Hh + nH + q * 16 + 8);
      f16x8 hl0 = *(const f16x8*)(Hl + nH + q * 16);
      f16x8 hl1 = *(const f16x8*)(Hl + nH + q * 16 + 8);
      float pacc = 0.f;
      #pragma unroll
      for (int j = 0; j < 8; ++j) pacc += fcW[q * 16 + j] * ((float)hh0[j] + (float)hl0[j]);
      #pragma unroll
      for (int j = 0; j < 8; ++j) pacc += fcW[q * 16 + 8 + j] * ((float)hh1[j] + (float)hl1[j]);
      pacc += __shfl_down(pacc, 32);
      pacc += __shfl_down(pacc, 16);
      if (lane < BT) {
        pacc += fcb0;
        out[(b0g + lane) * HZ + hz] = pacc;
        dins[lane] = pacc;
      }
    }
    __syncthreads();
  }
}

extern "C" void kernel_launch(void* const* d_in, const int* in_sizes, int n_in,
                              void* d_out, int out_size, void* d_ws, size_t ws_size,
                              hipStream_t stream) {
  (void)in_sizes; (void)n_in; (void)d_ws; (void)ws_size; (void)out_size;
  const float* x     = (const float*)d_in[0];
  const float* eWih0 = (const float*)d_in[1];
  const float* eWhh0 = (const float*)d_in[2];
  const float* eb0   = (const float*)d_in[3];
  const float* eWih1 = (const float*)d_in[4];
  const float* eWhh1 = (const float*)d_in[5];
  const float* eb1   = (const float*)d_in[6];
  const float* dWih0 = (const float*)d_in[7];
  const float* dWhh0 = (const float*)d_in[8];
  const float* db0   = (const float*)d_in[9];
  const float* dWih1 = (const float*)d_in[10];
  const float* dWhh1 = (const float*)d_in[11];
  const float* db1   = (const float*)d_in[12];
  const float* fcW   = (const float*)d_in[13];
  const float* fcb   = (const float*)d_in[14];
  float* out = (float*)d_out;

  dim3 grid(4096 / BT);   // 256 blocks = 1/CU
  dim3 block(1024);       // 16 waves = 4 waves/SIMD
  hipLaunchKernelGGL(lstm_fused, grid, block, 0, stream,
                     x, eWih0, eWhh0, eb0, eWih1, eWhh1, eb1,
                     dWih0, dWhh0, db0, dWih1, dWhh1, db1, fcW, fcb, out);
}

// Round 8
// 470.271 us; speedup vs baseline: 1.3776x; 1.3776x over previous
//
#include <hip/hip_runtime.h>

// EncoderDecoderLSTM on MI355X — R8: R6 base (best, 571us) + h-lo plane dropped.
// h stored single f16 in LDS (c-state stays fp32 in regs -> recurrence exact;
// only the matmul input is quantized, 2^-12, injected through a contractive
// recurrence). Weights keep hi+lo (A*Whi + A*Wlo = weight-exact, 2 MFMAs/term).
// Per slot vs R6: MFMA 72->48 per SIMD-pair, DS frag reads 48->24 b128 (the
// critical-path drain), h writes 64->32, split VALU gone.
// Structure (R6-proven): 512 thr, grid 256 (1 block/CU, 2 waves/SIMD, 256-reg
// budget, no spill). Waves 0-3 layer0 slot s, waves 4-7 layer1 slot s-1, one
// barrier/slot, static parity (unroll x2), native v_exp/v_rcp activations.
// R7 lesson: gate-split waves duplicate A-frag reads -> per-CU LDS pipe pays
// twice (conflicts 1.9e7->4.9e7, dur 571->648). Don't add waves that re-read.

typedef _Float16 f16x8 __attribute__((ext_vector_type(8)));
typedef float    f32x4 __attribute__((ext_vector_type(4)));

static constexpr int T_ENC = 365;
static constexpr int HZ    = 7;
static constexpr int BT    = 16;   // batch tile per block
static constexpr int HPAD  = 72;   // padded f16 row stride (144 B)

#if __has_builtin(__builtin_amdgcn_exp2f)
__device__ __forceinline__ float fexp2(float x) { return __builtin_amdgcn_exp2f(x); }
#else
__device__ __forceinline__ float fexp2(float x) { return __exp2f(x); }
#endif
#if __has_builtin(__builtin_amdgcn_rcpf)
__device__ __forceinline__ float frcp(float x) { return __builtin_amdgcn_rcpf(x); }
#else
__device__ __forceinline__ float frcp(float x) { return 1.0f / x; }
#endif

// sigmoid: rcp(1+2^(-x*log2e)). Tails exact (exp2 inf->rcp 0; exp2 0->1).
__device__ __forceinline__ float sigf(float v) {
  return frcp(1.0f + fexp2(v * -1.442695040888963f));
}
// tanh: (t-1)*rcp(t+1), t=2^(2x*log2e). Clamp +-30 so t stays finite.
__device__ __forceinline__ float tanh_fast(float v) {
  v = fminf(fmaxf(v, -30.0f), 30.0f);
  float t = fexp2(v * 2.885390081777927f);
  return (t - 1.0f) * frcp(t + 1.0f);
}

// acc += A * (Whi + Wlo)  — weight-exact, A single-plane f16
__device__ __forceinline__ f32x4 mmw(f16x8 a, f16x8 whi, f16x8 wlo, f32x4 acc) {
  acc = __builtin_amdgcn_mfma_f32_16x16x32_f16(a, whi, acc, 0, 0, 0);
  acc = __builtin_amdgcn_mfma_f32_16x16x32_f16(a, wlo, acc, 0, 0, 0);
  return acc;
}

__global__ __launch_bounds__(512, 2)
void lstm_fused(const float* __restrict__ x,
                const float* __restrict__ eWih0, const float* __restrict__ eWhh0,
                const float* __restrict__ eb0,
                const float* __restrict__ eWih1, const float* __restrict__ eWhh1,
                const float* __restrict__ eb1,
                const float* __restrict__ dWih0, const float* __restrict__ dWhh0,
                const float* __restrict__ db0,
                const float* __restrict__ dWih1, const float* __restrict__ dWhh1,
                const float* __restrict__ db1,
                const float* __restrict__ fcW, const float* __restrict__ fcb,
                float* __restrict__ out)
{
  __shared__ __align__(16) float    xs[T_ENC * BT];                 // x transposed [t][b]
  __shared__ __align__(16) _Float16 h0s[2][BT * HPAD];              // h0, single f16 plane
  __shared__ __align__(16) _Float16 h1s[2][BT * HPAD];              // h1
  __shared__ __align__(16) float    dins[BT];

  const int tid  = threadIdx.x;
  const int lane = tid & 63;
  const int wv   = tid >> 6;        // wave 0..7; 0-3 = layer0 group, 4-7 = layer1 group
  const int wg   = wv & 3;          // index within group
  const int n    = lane & 15;       // tile col (gate row) / A-row (batch) index
  const int q    = lane >> 4;       // quad
  const int b0g  = blockIdx.x * BT;
  const int wbase = wg * 16 + n;    // D-layout j column for h writes
  const int nH   = n * HPAD;

  // Stage x[b][t] -> xs[t][b]
  for (int i = tid; i < T_ENC * BT; i += 512) {
    int b = i / T_ENC;
    int t = i - b * T_ENC;
    xs[t * BT + b] = x[(b0g + b) * T_ENC + t];
  }
  for (int i = tid; i < 2 * BT * HPAD; i += 512) {
    ((_Float16*)h0s)[i] = (_Float16)0.f;
    ((_Float16*)h1s)[i] = (_Float16)0.f;
  }
  if (tid < BT) dins[tid] = 0.f;

  // Weight registers (hi+lo, weight-exact):
  //   group A (layer0): WA = Whh0 ;               wih0v = Wih0 col, biasv = b0
  //   group B (layer1): WA = Wih1 ; WB = Whh1 ;   biasv = b1
  f16x8 WAhi[4][2], WAlo[4][2], WBhi[4][2], WBlo[4][2];
  float biasv[4], wih0v[4];

  auto splitrow = [&](const float* p, f16x8& hi, f16x8& lo) {
    #pragma unroll
    for (int j = 0; j < 8; ++j) {
      float v = p[j];
      _Float16 h = (_Float16)v;
      hi[j] = h; lo[j] = (_Float16)(v - (float)h);
    }
  };
  auto loadA = [&](const float* Wih0_, const float* Whh0_, const float* b0_) {
    #pragma unroll
    for (int ti = 0; ti < 4; ++ti) {
      const int r = (ti * 4 + wg) * 16 + n;
      biasv[ti] = b0_[r];
      wih0v[ti] = Wih0_[r];
      #pragma unroll
      for (int kc = 0; kc < 2; ++kc)
        splitrow(Whh0_ + r * 64 + kc * 32 + q * 8, WAhi[ti][kc], WAlo[ti][kc]);
    }
  };
  auto loadB = [&](const float* Wih1_, const float* Whh1_, const float* b1_) {
    #pragma unroll
    for (int ti = 0; ti < 4; ++ti) {
      const int r = (ti * 4 + wg) * 16 + n;
      biasv[ti] = b1_[r];
      #pragma unroll
      for (int kc = 0; kc < 2; ++kc) {
        splitrow(Wih1_ + r * 64 + kc * 32 + q * 8, WAhi[ti][kc], WAlo[ti][kc]);
        splitrow(Whh1_ + r * 64 + kc * 32 + q * 8, WBhi[ti][kc], WBlo[ti][kc]);
      }
    }
  };

  if (wv < 4) loadA(eWih0, eWhh0, eb0);
  else        loadB(eWih1, eWhh1, eb1);

  f32x4 cst = {0.f, 0.f, 0.f, 0.f};   // c0 on group A, c1 on group B

  // layer0 step: gates = bias + x*wih0 + h0 @ Whh0^T ; h published single-f16
  auto stepA = [&](const _Float16* H, _Float16* O, f32x4 xv) {
    const _Float16* hp = H + nH;
    f16x8 a0 = *(const f16x8*)(hp + q * 8);
    f16x8 a1 = *(const f16x8*)(hp + 32 + q * 8);
    f32x4 g[4];
    #pragma unroll
    for (int ti = 0; ti < 4; ++ti) {
      f32x4 a;
      #pragma unroll
      for (int r = 0; r < 4; ++r) a[r] = xv[r] * wih0v[ti] + biasv[ti];
      a = mmw(a0, WAhi[ti][0], WAlo[ti][0], a);
      a = mmw(a1, WAhi[ti][1], WAlo[ti][1], a);
      g[ti] = a;
    }
    #pragma unroll
    for (int r = 0; r < 4; ++r) {
      float c = sigf(g[1][r]) * cst[r] + sigf(g[0][r]) * tanh_fast(g[2][r]);
      cst[r] = c;
      float h = sigf(g[3][r]) * tanh_fast(c);
      O[(q * 4 + r) * HPAD + wbase] = (_Float16)h;
    }
  };

  // layer1 step: gates = bias + h0 @ Wih1^T + h1 @ Whh1^T
  auto stepB = [&](const _Float16* H0, const _Float16* H1, _Float16* O) {
    const _Float16* p0 = H0 + nH;
    const _Float16* p1 = H1 + nH;
    f16x8 b0 = *(const f16x8*)(p0 + q * 8);
    f16x8 b1 = *(const f16x8*)(p0 + 32 + q * 8);
    f16x8 a0 = *(const f16x8*)(p1 + q * 8);
    f16x8 a1 = *(const f16x8*)(p1 + 32 + q * 8);
    f32x4 g[4];
    #pragma unroll
    for (int ti = 0; ti < 4; ++ti) {
      f32x4 a;
      #pragma unroll
      for (int r = 0; r < 4; ++r) a[r] = biasv[ti];
      a = mmw(b0, WAhi[ti][0], WAlo[ti][0], a);
      a = mmw(b1, WAhi[ti][1], WAlo[ti][1], a);
      a = mmw(a0, WBhi[ti][0], WBlo[ti][0], a);
      a = mmw(a1, WBhi[ti][1], WBlo[ti][1], a);
      g[ti] = a;
    }
    #pragma unroll
    for (int r = 0; r < 4; ++r) {
      float c = sigf(g[1][r]) * cst[r] + sigf(g[0][r]) * tanh_fast(g[2][r]);
      cst[r] = c;
      float h = sigf(g[3][r]) * tanh_fast(c);
      O[(q * 4 + r) * HPAD + wbase] = (_Float16)h;
    }
  };

  __syncthreads();

  // ---- encoder, unrolled x2 with static parity ----
  // slot s: A reads h0[(s&1)^1] writes h0[s&1];
  // B (t=s-1) reads h0[t&1], h1[(t&1)^1], writes h1[t&1].

  // s = 0 (even): A only. h0[1] is zeros.
  if (wv < 4) {
    f32x4 xv = *(const f32x4*)(xs + q * 4);
    stepA(h0s[1], h0s[0], xv);
  }
  __syncthreads();

  // s = 1..364 as 182 (odd, even) pairs — both groups always active.
  for (int s = 1; s <= 363; s += 2) {
    // slot s (odd): A h0[0]->h0[1] ; B(t even) h0[0],h1[1] -> h1[0]
    if (wv < 4) {
      f32x4 xv = *(const f32x4*)(xs + s * BT + q * 4);
      stepA(h0s[0], h0s[1], xv);
    } else {
      stepB(h0s[0], h1s[1], h1s[0]);
    }
    __syncthreads();
    // slot s+1 (even): A h0[1]->h0[0] ; B(t odd) h0[1],h1[0] -> h1[1]
    if (wv < 4) {
      f32x4 xv = *(const f32x4*)(xs + (s + 1) * BT + q * 4);
      stepA(h0s[1], h0s[0], xv);
    } else {
      stepB(h0s[1], h1s[0], h1s[1]);
    }
    __syncthreads();
  }

  // s = 365 (odd): A loads decoder weights (idle slot); B(t=364 even):
  // h0[0], h1[1] -> h1[0].
  if (wv < 4) loadA(dWih0, dWhh0, db0);
  else        stepB(h0s[0], h1s[1], h1s[0]);
  __syncthreads();

  // ---- decoder ---- (latest h0, h1 live in parity-0 buffers)
  if (wv >= 4) loadB(dWih1, dWhh1, db1);
  float fcw[16];
  #pragma unroll
  for (int j = 0; j < 16; ++j) fcw[j] = fcW[q * 16 + j];
  const float fcb0 = fcb[0];

  #pragma unroll 1
  for (int hz = 0; hz < HZ; ++hz) {
    const int p = hz & 1;           // latest state parity at step entry
    if (wv < 4) {
      f32x4 dv = *(const f32x4*)(dins + q * 4);
      stepA(h0s[p], h0s[1 - p], dv);
    }
    __syncthreads();
    if (wv >= 4) {
      stepB(h0s[1 - p], h1s[p], h1s[1 - p]);
    }
    __syncthreads();
    if (wv == 0) {
      const _Float16* Hh = h1s[1 - p];
      f16x8 hh0 = *(const f16x8*)(Hh + nH + q * 16);
      f16x8 hh1 = *(const f16x8*)(Hh + nH + q * 16 + 8);
      float pacc = 0.f;
      #pragma unroll
      for (int j = 0; j < 8; ++j) pacc += fcw[j] * (float)hh0[j];
      #pragma unroll
      for (int j = 0; j < 8; ++j) pacc += fcw[8 + j] * (float)hh1[j];
      pacc += __shfl_down(pacc, 32);
      pacc += __shfl_down(pacc, 16);
      if (lane < BT) {
        pacc += fcb0;
        out[(b0g + lane) * HZ + hz] = pacc;
        dins[lane] = pacc;
      }
    }
    __syncthreads();
  }
}

extern "C" void kernel_launch(void* const* d_in, const int* in_sizes, int n_in,
                              void* d_out, int out_size, void* d_ws, size_t ws_size,
                              hipStream_t stream) {
  (void)in_sizes; (void)n_in; (void)d_ws; (void)ws_size; (void)out_size;
  const float* x     = (const float*)d_in[0];
  const float* eWih0 = (const float*)d_in[1];
  const float* eWhh0 = (const float*)d_in[2];
  const float* eb0   = (const float*)d_in[3];
  const float* eWih1 = (const float*)d_in[4];
  const float* eWhh1 = (const float*)d_in[5];
  const float* eb1   = (const float*)d_in[6];
  const float* dWih0 = (const float*)d_in[7];
  const float* dWhh0 = (const float*)d_in[8];
  const float* db0   = (const float*)d_in[9];
  const float* dWih1 = (const float*)d_in[10];
  const float* dWhh1 = (const float*)d_in[11];
  const float* db1   = (const float*)d_in[12];
  const float* fcW   = (const float*)d_in[13];
  const float* fcb   = (const float*)d_in[14];
  float* out = (float*)d_out;

  dim3 grid(4096 / BT);   // 256 blocks = 1/CU
  dim3 block(512);        // 8 waves: 4 layer0 + 4 layer1
  hipLaunchKernelGGL(lstm_fused, grid, block, 0, stream,
                     x, eWih0, eWhh0, eb0, eWih1, eWhh1, eb1,
                     dWih0, dWhh0, db0, dWih1, dWhh1, db1, fcW, fcb, out);
}